// Round 6
// baseline (323.267 us; speedup 1.0000x reference)
//
#include <hip/hip_runtime.h>
#include <math.h>

#define OUT 7
#define NVOX 343          // 7*7*7
#define PZ 14             // 7 voxels * 2 sub-samples along collapsed axis
#define ROWCAP 384        // max region rows (product of two smaller axes' counts)
#define BCAP (ROWCAP*PZ)  // 5376 floats = 21 KB
#define BLK 384           // 6 waves

__device__ __forceinline__ int sel3i(int a, int v0, int v1, int v2) {
    return a == 0 ? v0 : (a == 1 ? v1 : v2);
}

__device__ __forceinline__ void axis_samp(float c, float fdim, int dim,
                                          int& lo, float& w0, float& w1) {
    float valid = (c > -1.0f && c < fdim) ? 1.0f : 0.0f;
    float cc = fminf(fmaxf(c, 0.0f), fdim - 1.0f);
    lo = (int)floorf(cc);
    float fr = cc - (float)lo;
    w0 = (1.0f - fr) * valid;
    w1 = fr * valid;     // == 0 whenever hi would clamp (fr==0 at lo==dim-1)
}

__global__ __launch_bounds__(BLK) void roi_align_ms3d_sep_kernel(
    const float* __restrict__ f0, const float* __restrict__ f1,
    const float* __restrict__ f2, const float* __restrict__ f3,
    const float* __restrict__ boxes, float* __restrict__ out,
    int N, int C, int d0, int d1, int d2_, int d3)
{
    __shared__ __align__(16) float B[BCAP];
    __shared__ int rowsrc[ROWCAP];
    __shared__ float4 ztab[PZ];    // {off_lo(F units), off_hi, w0, w1} along collapsed axis
    __shared__ float4 t2tab[PZ];   // {off_lo(B units), off_hi, w0, w1} axis a2
    __shared__ float4 t3tab[PZ];   // {off_lo(B units), off_hi, w0, w1} axis a3

    const int c   = blockIdx.x;   // channel
    const int n   = blockIdx.y;   // box
    const int tid = threadIdx.x;

    const float* bp = boxes + n * 6;
    float b0 = bp[0], b1 = bp[1], b2 = bp[2];
    float b3 = bp[3], b4 = bp[4], b5 = bp[5];

    // level_map
    float vol = (b3 - b0) * (b4 - b1) * (b5 - b2);
    float s = cbrtf(vol);
    float lvl = floorf(4.0f + log2f(s / 160.0f) + 1e-6f);
    lvl = fminf(fmaxf(lvl, 2.0f), 5.0f);
    int l = (int)lvl - 2;

    const float* f;
    int dim;
    float scale;
    if (l == 0)      { f = f0; dim = d0;  scale = 0.25f;    }
    else if (l == 1) { f = f1; dim = d1;  scale = 0.125f;   }
    else if (l == 2) { f = f2; dim = d2_; scale = 0.0625f;  }
    else             { f = f3; dim = d3;  scale = 0.03125f; }

    const float fdim = (float)dim;
    const int dsq = dim * dim;
    const size_t dcube = (size_t)dim * dsq;
    const float* fc = f + (size_t)c * dcube;

    float st0 = b0 * scale, st1 = b1 * scale, st2 = b2 * scale;
    float e0 = fmaxf(b3 * scale - st0, 1.0f);
    float e1 = fmaxf(b4 * scale - st1, 1.0f);
    float e2 = fmaxf(b5 * scale - st2, 1.0f);
    float bs0 = e0 * (1.0f / OUT), bs1 = e1 * (1.0f / OUT), bs2 = e2 * (1.0f / OUT);

    // region bounds per axis (lattice points touched by clipped sub-samples)
    #define RB(stv, bsv, lo_, n_) { \
        int lo = (int)floorf(fminf(fmaxf((stv) + 0.25f * (bsv), 0.0f), fdim - 1.0f)); \
        int hi = min((int)floorf(fminf(fmaxf((stv) + 6.75f * (bsv), 0.0f), fdim - 1.0f)) + 1, dim - 1); \
        lo_ = lo; n_ = hi - lo + 1; }
    int r0_, r1_, r2r; int q0, q1, q2;
    RB(st0, bs0, r0_, q0);
    RB(st1, bs1, r1_, q1);
    RB(st2, bs2, r2r, q2);
    #undef RB

    // collapse the largest axis
    int a1 = (q0 >= q1) ? (q0 >= q2 ? 0 : 2) : (q1 >= q2 ? 1 : 2);
    int a2 = (a1 == 0) ? 1 : 0;
    int a3 = (a1 == 2) ? 1 : 2;

    int n2 = sel3i(a2, q0, q1, q2);
    int n3 = sel3i(a3, q0, q1, q2);
    int nrows = n2 * n3;

    if (nrows <= ROWCAP) {
        // ---- channel-invariant tables: 42 threads, one entry each ----
        if (tid < 3 * PZ) {
            int slot = tid / PZ;            // 0 -> a1, 1 -> a2, 2 -> a3
            int k = tid - slot * PZ;
            int a = sel3i(slot, a1, a2, a3);
            float stv = sel3i(a, 0, 1, 2) == 0 ? st0 : (a == 1 ? st1 : st2);
            float bsv = (a == 0) ? bs0 : (a == 1 ? bs1 : bs2);
            int org = sel3i(a, r0_, r1_, r2r);
            int o = k >> 1, r = k & 1;
            float cc = stv + ((float)o + (0.25f + 0.5f * (float)r)) * bsv;
            int lo; float w0, w1;
            axis_samp(cc, fdim, dim, lo, w0, w1);
            int rel  = lo - org;
            int relh = min(lo + 1, dim - 1) - org;
            int mul = (slot == 0) ? sel3i(a, dsq, dim, 1)
                    : (slot == 1) ? (n3 * PZ) : PZ;
            float4 e;
            e.x = __int_as_float(rel  * mul);
            e.y = __int_as_float(relh * mul);
            e.z = w0; e.w = w1;
            if (slot == 0) ztab[k] = e;
            else if (slot == 1) t2tab[k] = e;
            else t3tab[k] = e;
        }

        // ---- row source offsets (absolute F offset of (i2,i3) at a1-origin) ----
        int s1 = sel3i(a1, dsq, dim, 1);
        int s2 = sel3i(a2, dsq, dim, 1);
        int s3 = sel3i(a3, dsq, dim, 1);
        int baseoff = sel3i(a1, r0_, r1_, r2r) * s1
                    + sel3i(a2, r0_, r1_, r2r) * s2
                    + sel3i(a3, r0_, r1_, r2r) * s3;
        float rn3 = 1.0f / (float)n3;
        for (int row = tid; row < nrows; row += BLK) {
            int i2 = (int)((float)row * rn3);
            int i3 = row - i2 * n3;
            if (i3 < 0)       { i2 -= 1; i3 += n3; }
            else if (i3 >= n3){ i2 += 1; i3 -= n3; }
            rowsrc[row] = baseoff + i2 * s2 + i3 * s3;
        }
        __syncthreads();

        // ---- staging with fused lerp along collapsed axis ----
        int nB = nrows * PZ;
        for (int e = tid; e < nB; e += BLK) {
            int row = e / PZ;          // constant divisor -> magic mul
            int k = e - row * PZ;
            float4 ze = ztab[k];
            int base = rowsrc[row];
            B[e] = ze.z * fc[base + __float_as_int(ze.x)]
                 + ze.w * fc[base + __float_as_int(ze.y)];
        }
        __syncthreads();

        // ---- bilinear interp from B (z already resolved) ----
        if (tid < NVOX) {
            int o2 = tid % OUT;
            int t7 = tid / OUT;
            int o1 = t7 % OUT;
            int o0 = t7 / OUT;
            int colB = 2 * sel3i(a1, o0, o1, o2);
            int i2b  = 2 * sel3i(a2, o0, o1, o2);
            int i3b  = 2 * sel3i(a3, o0, o1, o2);

            float acc = 0.0f;
            #pragma unroll
            for (int rr2 = 0; rr2 < 2; ++rr2) {
                float4 t2 = t2tab[i2b + rr2];
                int off2l = __float_as_int(t2.x), off2h = __float_as_int(t2.y);
                #pragma unroll
                for (int rr3 = 0; rr3 < 2; ++rr3) {
                    float4 t3v = t3tab[i3b + rr3];
                    int off3l = __float_as_int(t3v.x), off3h = __float_as_int(t3v.y);
                    const float2 vll = *(const float2*)&B[off2l + off3l + colB];
                    const float2 vlh = *(const float2*)&B[off2l + off3h + colB];
                    const float2 vhl = *(const float2*)&B[off2h + off3l + colB];
                    const float2 vhh = *(const float2*)&B[off2h + off3h + colB];
                    float sll = vll.x + vll.y;
                    float slh = vlh.x + vlh.y;
                    float shl = vhl.x + vhl.y;
                    float shh = vhh.x + vhh.y;
                    acc += t2.z * (t3v.z * sll + t3v.w * slh)
                         + t2.w * (t3v.z * shl + t3v.w * shh);
                }
            }
            out[((size_t)n * C + c) * NVOX + tid] = acc * 0.125f;
        }
    } else {
        // ---- safety net (degenerate huge rows): direct global trilinear ----
        if (tid < NVOX) {
            int o2 = tid % OUT;
            int t7 = tid / OUT;
            int o1 = t7 % OUT;
            int o0 = t7 / OUT;
            int xl[2], yl[2], zl[2];
            float xw0[2], xw1[2], yw0[2], yw1[2], zw0[2], zw1[2];
            #pragma unroll
            for (int r = 0; r < 2; ++r) {
                float off = 0.25f + 0.5f * (float)r;
                axis_samp(st0 + ((float)o0 + off) * bs0, fdim, dim, xl[r], xw0[r], xw1[r]);
                axis_samp(st1 + ((float)o1 + off) * bs1, fdim, dim, yl[r], yw0[r], yw1[r]);
                axis_samp(st2 + ((float)o2 + off) * bs2, fdim, dim, zl[r], zw0[r], zw1[r]);
            }
            float acc = 0.0f;
            #pragma unroll
            for (int rx2 = 0; rx2 < 2; ++rx2) {
                const float* pxl = fc + (size_t)xl[rx2] * dsq;
                const float* pxh = fc + (size_t)min(xl[rx2] + 1, dim - 1) * dsq;
                float wx0 = xw0[rx2], wx1 = xw1[rx2];
                #pragma unroll
                for (int ry2 = 0; ry2 < 2; ++ry2) {
                    int ryl = yl[ry2] * dim;
                    int ryh = min(yl[ry2] + 1, dim - 1) * dim;
                    float wy0 = yw0[ry2], wy1 = yw1[ry2];
                    #pragma unroll
                    for (int rz2 = 0; rz2 < 2; ++rz2) {
                        int bZL = zl[rz2];
                        int bZH = min(zl[rz2] + 1, dim - 1);
                        float wz0 = zw0[rz2], wz1 = zw1[rz2];
                        float v000 = pxl[ryl + bZL];
                        float v001 = pxl[ryl + bZH];
                        float v010 = pxl[ryh + bZL];
                        float v011 = pxl[ryh + bZH];
                        float v100 = pxh[ryl + bZL];
                        float v101 = pxh[ryl + bZH];
                        float v110 = pxh[ryh + bZL];
                        float v111 = pxh[ryh + bZH];
                        float vx0 = wy0 * (wz0 * v000 + wz1 * v001)
                                  + wy1 * (wz0 * v010 + wz1 * v011);
                        float vx1 = wy0 * (wz0 * v100 + wz1 * v101)
                                  + wy1 * (wz0 * v110 + wz1 * v111);
                        acc += wx0 * vx0 + wx1 * vx1;
                    }
                }
            }
            out[((size_t)n * C + c) * NVOX + tid] = acc * 0.125f;
        }
    }
}

extern "C" void kernel_launch(void* const* d_in, const int* in_sizes, int n_in,
                              void* d_out, int out_size, void* d_ws, size_t ws_size,
                              hipStream_t stream) {
    const float* f0 = (const float*)d_in[0];
    const float* f1 = (const float*)d_in[1];
    const float* f2 = (const float*)d_in[2];
    const float* f3 = (const float*)d_in[3];
    const float* boxes = (const float*)d_in[4];
    float* out = (float*)d_out;

    int N = in_sizes[4] / 6;
    int C = out_size / (N * NVOX);

    auto cdim = [&](int sz) {
        int per_c = sz / C;
        return (int)(cbrtf((float)per_c) + 0.5f);
    };
    int d0 = cdim(in_sizes[0]);
    int d1 = cdim(in_sizes[1]);
    int d2 = cdim(in_sizes[2]);
    int d3 = cdim(in_sizes[3]);

    dim3 grid(C, N);   // one block per (box, channel)
    roi_align_ms3d_sep_kernel<<<grid, BLK, 0, stream>>>(f0, f1, f2, f3, boxes, out,
                                                        N, C, d0, d1, d2, d3);
}

// Round 7
// 188.690 us; speedup vs baseline: 1.7132x; 1.7132x over previous
//
#include <hip/hip_runtime.h>
#include <math.h>

#define OUT 7
#define NVOX 343          // 7*7*7
#define NCHUNK 22         // ceil(343/16) voxel chunks per box

// ---------------- fallback (R4-proven, 206 us) ----------------
#define LDSF 11776
#define FBLK 512

__device__ __forceinline__ void axis_samp(float c, float fdim, int dim,
                                          int& lo, float& w0, float& w1) {
    float valid = (c > -1.0f && c < fdim) ? 1.0f : 0.0f;
    float cc = fminf(fmaxf(c, 0.0f), fdim - 1.0f);
    lo = (int)floorf(cc);
    float fr = cc - (float)lo;
    w0 = (1.0f - fr) * valid;
    w1 = fr * valid;     // == 0 whenever hi would clamp
}

__device__ __forceinline__ void box_setup(const float* bp, float fd0, float fd1,
                                          float fd2, float fd3,
                                          int d0, int d1, int d2_, int d3,
                                          int& l, int& dim, float& fdim,
                                          float& st0, float& st1, float& st2,
                                          float& bs0, float& bs1, float& bs2) {
    float b0 = bp[0], b1 = bp[1], b2 = bp[2];
    float b3 = bp[3], b4 = bp[4], b5 = bp[5];
    float vol = (b3 - b0) * (b4 - b1) * (b5 - b2);
    float s = cbrtf(vol);
    float lvl = floorf(4.0f + log2f(s / 160.0f) + 1e-6f);
    lvl = fminf(fmaxf(lvl, 2.0f), 5.0f);
    l = (int)lvl - 2;
    float scale;
    if (l == 0)      { dim = d0;  scale = 0.25f;    }
    else if (l == 1) { dim = d1;  scale = 0.125f;   }
    else if (l == 2) { dim = d2_; scale = 0.0625f;  }
    else             { dim = d3;  scale = 0.03125f; }
    fdim = (float)dim;
    st0 = b0 * scale; st1 = b1 * scale; st2 = b2 * scale;
    float e0 = fmaxf(b3 * scale - st0, 1.0f);
    float e1 = fmaxf(b4 * scale - st1, 1.0f);
    float e2 = fmaxf(b5 * scale - st2, 1.0f);
    bs0 = e0 * (1.0f / OUT); bs1 = e1 * (1.0f / OUT); bs2 = e2 * (1.0f / OUT);
}

__global__ __launch_bounds__(FBLK) void roi_align_fallback_kernel(
    const float* __restrict__ f0, const float* __restrict__ f1,
    const float* __restrict__ f2, const float* __restrict__ f3,
    const float* __restrict__ boxes, float* __restrict__ out,
    int N, int C, int d0, int d1, int d2_, int d3)
{
    __shared__ float lds[LDSF];
    const int c   = blockIdx.x;
    const int n   = blockIdx.y;
    const int tid = threadIdx.x;

    int l, dim; float fdim, st0, st1, st2, bs0, bs1, bs2;
    box_setup(boxes + n * 6, 0, 0, 0, 0, d0, d1, d2_, d3,
              l, dim, fdim, st0, st1, st2, bs0, bs1, bs2);
    const float* f = (l == 0) ? f0 : (l == 1) ? f1 : (l == 2) ? f2 : f3;

    const int dsq = dim * dim;
    const size_t dcube = (size_t)dim * dsq;
    const float* fc = f + (size_t)c * dcube;

    int x0 = (int)floorf(fminf(fmaxf(st0 + 0.25f * bs0, 0.0f), fdim - 1.0f));
    int x1 = min((int)floorf(fminf(fmaxf(st0 + 6.75f * bs0, 0.0f), fdim - 1.0f)) + 1, dim - 1);
    int y0 = (int)floorf(fminf(fmaxf(st1 + 0.25f * bs1, 0.0f), fdim - 1.0f));
    int y1 = min((int)floorf(fminf(fmaxf(st1 + 6.75f * bs1, 0.0f), fdim - 1.0f)) + 1, dim - 1);
    int z0 = (int)floorf(fminf(fmaxf(st2 + 0.25f * bs2, 0.0f), fdim - 1.0f));
    int z1 = min((int)floorf(fminf(fmaxf(st2 + 6.75f * bs2, 0.0f), fdim - 1.0f)) + 1, dim - 1);

    int nx = x1 - x0 + 1, ny = y1 - y0 + 1, nz = z1 - z0 + 1;
    int nzp = nz + 1;
    int nynzp = ny * nzp;
    int nrows = nx * ny;
    int nregp = nrows * nzp;

    int xl[2], yl[2], zl[2];
    float xw0[2], xw1[2], yw0[2], yw1[2], zw0[2], zw1[2];
    if (tid < NVOX) {
        int oz = tid % OUT;
        int oy = (tid / OUT) % OUT;
        int ox = tid / (OUT * OUT);
        #pragma unroll
        for (int r = 0; r < 2; ++r) {
            float off = 0.25f + 0.5f * (float)r;
            axis_samp(st0 + ((float)ox + off) * bs0, fdim, dim, xl[r], xw0[r], xw1[r]);
            axis_samp(st1 + ((float)oy + off) * bs1, fdim, dim, yl[r], yw0[r], yw1[r]);
            axis_samp(st2 + ((float)oz + off) * bs2, fdim, dim, zl[r], zw0[r], zw1[r]);
        }
    }

    if (nregp <= LDSF) {
        float rnzp = 1.0f / (float)nzp;
        float rny  = 1.0f / (float)ny;
        for (int e = tid; e < nregp; e += FBLK) {
            int row = (int)((float)e * rnzp);
            int zz = e - row * nzp;
            if (zz < 0)        { row -= 1; zz += nzp; }
            else if (zz >= nzp){ row += 1; zz -= nzp; }
            int rx = (int)((float)row * rny);
            int ry = row - rx * ny;
            if (ry < 0)        { rx -= 1; ry += ny; }
            else if (ry >= ny) { rx += 1; ry -= ny; }
            int zsrc = min(zz, nz - 1);
            lds[e] = fc[((size_t)(x0 + rx) * dim + (y0 + ry)) * dim + (z0 + zsrc)];
        }
        __syncthreads();

        if (tid < NVOX) {
            int XL[2], XH[2], YL[2], YH[2], ZL[2];
            #pragma unroll
            for (int r = 0; r < 2; ++r) {
                XL[r] = (xl[r] - x0) * nynzp;
                XH[r] = (min(xl[r] + 1, dim - 1) - x0) * nynzp;
                YL[r] = (yl[r] - y0) * nzp;
                YH[r] = (min(yl[r] + 1, dim - 1) - y0) * nzp;
                ZL[r] = zl[r] - z0;
            }
            float acc = 0.0f;
            #pragma unroll
            for (int rx2 = 0; rx2 < 2; ++rx2) {
                #pragma unroll
                for (int ry2 = 0; ry2 < 2; ++ry2) {
                    #pragma unroll
                    for (int rz2 = 0; rz2 < 2; ++rz2) {
                        const float* pll = lds + (XL[rx2] + YL[ry2] + ZL[rz2]);
                        const float* plh = lds + (XL[rx2] + YH[ry2] + ZL[rz2]);
                        const float* phl = lds + (XH[rx2] + YL[ry2] + ZL[rz2]);
                        const float* phh = lds + (XH[rx2] + YH[ry2] + ZL[rz2]);
                        float wz0 = zw0[rz2], wz1 = zw1[rz2];
                        float vx0 = yw0[ry2] * (wz0 * pll[0] + wz1 * pll[1])
                                  + yw1[ry2] * (wz0 * plh[0] + wz1 * plh[1]);
                        float vx1 = yw0[ry2] * (wz0 * phl[0] + wz1 * phl[1])
                                  + yw1[ry2] * (wz0 * phh[0] + wz1 * phh[1]);
                        acc += xw0[rx2] * vx0 + xw1[rx2] * vx1;
                    }
                }
            }
            out[((size_t)n * C + c) * NVOX + tid] = acc * 0.125f;
        }
    } else {
        if (tid < NVOX) {
            float acc = 0.0f;
            #pragma unroll
            for (int rx2 = 0; rx2 < 2; ++rx2) {
                const float* pxl = fc + (size_t)xl[rx2] * dsq;
                const float* pxh = fc + (size_t)min(xl[rx2] + 1, dim - 1) * dsq;
                float wx0 = xw0[rx2], wx1 = xw1[rx2];
                #pragma unroll
                for (int ry2 = 0; ry2 < 2; ++ry2) {
                    int ryl = yl[ry2] * dim;
                    int ryh = min(yl[ry2] + 1, dim - 1) * dim;
                    float wy0 = yw0[ry2], wy1 = yw1[ry2];
                    #pragma unroll
                    for (int rz2 = 0; rz2 < 2; ++rz2) {
                        int bZL = zl[rz2], bZH = min(zl[rz2] + 1, dim - 1);
                        float wz0 = zw0[rz2], wz1 = zw1[rz2];
                        float vx0 = wy0 * (wz0 * pxl[ryl + bZL] + wz1 * pxl[ryl + bZH])
                                  + wy1 * (wz0 * pxl[ryh + bZL] + wz1 * pxl[ryh + bZH]);
                        float vx1 = wy0 * (wz0 * pxh[ryl + bZL] + wz1 * pxh[ryl + bZH])
                                  + wy1 * (wz0 * pxh[ryh + bZL] + wz1 * pxh[ryh + bZH]);
                        acc += wx0 * vx0 + wx1 * vx1;
                    }
                }
            }
            out[((size_t)n * C + c) * NVOX + tid] = acc * 0.125f;
        }
    }
}

// ---------------- fast path: channel-last transpose + gather ----------------

// (C, S) -> (S, C) for C==64, S % 64 == 0
__global__ __launch_bounds__(256) void transpose_cl_kernel(
    const float* __restrict__ in, float* __restrict__ outT, int S)
{
    __shared__ float tile[64 * 65];
    int s0 = blockIdx.x * 64;
    int lane  = threadIdx.x & 63;
    int chunk = threadIdx.x >> 6;    // 0..3
    #pragma unroll
    for (int k = 0; k < 16; ++k) {
        int ch = chunk * 16 + k;
        tile[lane * 65 + ch] = in[(size_t)ch * S + s0 + lane];
    }
    __syncthreads();
    #pragma unroll
    for (int k = 0; k < 16; ++k) {
        int s = chunk * 16 + k;
        outT[(size_t)(s0 + s) * 64 + lane] = tile[s * 65 + lane];
    }
}

// grid: (N boxes, NCHUNK).  tid = slot*16 + quad; lanes 0-15 share a voxel.
__global__ __launch_bounds__(256, 4) void roi_align_cl_kernel(
    const float* __restrict__ ws, const float* __restrict__ boxes,
    float* __restrict__ out, int N, int C,
    int d0, int d1, int d2_, int d3,
    long off0, long off1, long off2, long off3)
{
    __shared__ float4 axtab[16 * 6];   // slot*6 + axis*2 + r : {offLo, offHi, w0, w1}
    __shared__ float ldsout[64 * 17];  // [ch*17 + slot]

    const int n    = blockIdx.x;       // box (x-major -> XCD-pinned per box)
    const int cb   = blockIdx.y * 16;  // chunk base voxel
    const int tid  = threadIdx.x;
    const int quad = tid & 15;
    const int slot = tid >> 4;

    int l, dim; float fdim, st0, st1, st2, bs0, bs1, bs2;
    box_setup(boxes + n * 6, 0, 0, 0, 0, d0, d1, d2_, d3,
              l, dim, fdim, st0, st1, st2, bs0, bs1, bs2);
    const float* ftl = ws + ((l == 0) ? off0 : (l == 1) ? off1 : (l == 2) ? off2 : off3);
    const int dsq = dim * dim;

    // ---- per-voxel axis tables (16 threads, one voxel each) ----
    if (quad == 0) {
        int v = min(cb + slot, NVOX - 1);
        int o2 = v % OUT;
        int t7 = v / OUT;
        int o1 = t7 % OUT;
        int o0 = t7 / OUT;
        const int stA[3] = { dsq * 64, dim * 64, 64 };
        const float oA[3] = { (float)o0, (float)o1, (float)o2 };
        const float sA[3] = { st0, st1, st2 };
        const float bA[3] = { bs0, bs1, bs2 };
        #pragma unroll
        for (int a = 0; a < 3; ++a) {
            #pragma unroll
            for (int r = 0; r < 2; ++r) {
                float cc = sA[a] + (oA[a] + (0.25f + 0.5f * (float)r)) * bA[a];
                int lo; float w0, w1;
                axis_samp(cc, fdim, dim, lo, w0, w1);
                float4 e;
                e.x = __int_as_float(lo * stA[a]);
                e.y = __int_as_float(min(lo + 1, dim - 1) * stA[a]);
                e.z = w0; e.w = w1;
                axtab[slot * 6 + a * 2 + r] = e;
            }
        }
    }
    __syncthreads();

    const bool active = (cb + slot) < NVOX;
    if (active) {
        const float4* tb = &axtab[slot * 6];
        float4 ex0 = tb[0], ex1 = tb[1], ey0 = tb[2], ey1 = tb[3], ez0 = tb[4], ez1 = tb[5];
        float xw[4] = { ex0.z, ex0.w, ex1.z, ex1.w };
        int   xo[4] = { __float_as_int(ex0.x), __float_as_int(ex0.y),
                        __float_as_int(ex1.x), __float_as_int(ex1.y) };
        float yw[4] = { ey0.z, ey0.w, ey1.z, ey1.w };
        int   yo[4] = { __float_as_int(ey0.x), __float_as_int(ey0.y),
                        __float_as_int(ey1.x), __float_as_int(ey1.y) };
        float zw[4] = { ez0.z, ez0.w, ez1.z, ez1.w };
        int   zq[4];
        #pragma unroll
        for (int k = 0; k < 4; ++k) {
            int zz = (k < 2) ? __float_as_int(k == 0 ? ez0.x : ez0.y)
                             : __float_as_int(k == 2 ? ez1.x : ez1.y);
            zq[k] = zz + quad * 4;
        }

        float4 acc = { 0.f, 0.f, 0.f, 0.f };
        #pragma unroll
        for (int i2 = 0; i2 < 4; ++i2) {
            float wxv = xw[i2];
            int a1 = xo[i2];
            #pragma unroll
            for (int j2 = 0; j2 < 4; ++j2) {
                float wxy = wxv * yw[j2];
                int a2 = a1 + yo[j2];
                #pragma unroll
                for (int k2 = 0; k2 < 4; ++k2) {
                    float w = wxy * zw[k2];
                    const float4 v = *(const float4*)(ftl + a2 + zq[k2]);
                    acc.x += w * v.x;
                    acc.y += w * v.y;
                    acc.z += w * v.z;
                    acc.w += w * v.w;
                }
            }
        }
        int chb = quad * 4;
        ldsout[(chb + 0) * 17 + slot] = acc.x * 0.125f;
        ldsout[(chb + 1) * 17 + slot] = acc.y * 0.125f;
        ldsout[(chb + 2) * 17 + slot] = acc.z * 0.125f;
        ldsout[(chb + 3) * 17 + slot] = acc.w * 0.125f;
    }
    __syncthreads();

    int nv = min(16, NVOX - cb);
    #pragma unroll
    for (int k = 0; k < 4; ++k) {
        int flat = k * 256 + tid;
        int ch = flat >> 4, vs = flat & 15;
        if (vs < nv)
            out[((size_t)n * C + ch) * NVOX + cb + vs] = ldsout[ch * 17 + vs];
    }
}

extern "C" void kernel_launch(void* const* d_in, const int* in_sizes, int n_in,
                              void* d_out, int out_size, void* d_ws, size_t ws_size,
                              hipStream_t stream) {
    const float* f0 = (const float*)d_in[0];
    const float* f1 = (const float*)d_in[1];
    const float* f2 = (const float*)d_in[2];
    const float* f3 = (const float*)d_in[3];
    const float* boxes = (const float*)d_in[4];
    float* out = (float*)d_out;

    int N = in_sizes[4] / 6;
    int C = out_size / (N * NVOX);

    auto cdim = [&](int sz) {
        int per_c = sz / C;
        return (int)(cbrtf((float)per_c) + 0.5f);
    };
    int d0 = cdim(in_sizes[0]);
    int d1 = cdim(in_sizes[1]);
    int d2 = cdim(in_sizes[2]);
    int d3 = cdim(in_sizes[3]);

    long S0 = (long)d0 * d0 * d0, S1 = (long)d1 * d1 * d1;
    long S2 = (long)d2 * d2 * d2, S3 = (long)d3 * d3 * d3;
    long off0 = 0, off1 = S0 * C, off2 = off1 + S1 * C, off3 = off2 + S2 * C;
    size_t need = (size_t)(off3 + S3 * C) * sizeof(float);

    bool fast = (C == 64) && (ws_size >= need) &&
                (S0 % 64 == 0) && (S1 % 64 == 0) && (S2 % 64 == 0) && (S3 % 64 == 0);

    if (fast) {
        float* ws = (float*)d_ws;
        transpose_cl_kernel<<<(int)(S0 / 64), 256, 0, stream>>>(f0, ws + off0, (int)S0);
        transpose_cl_kernel<<<(int)(S1 / 64), 256, 0, stream>>>(f1, ws + off1, (int)S1);
        transpose_cl_kernel<<<(int)(S2 / 64), 256, 0, stream>>>(f2, ws + off2, (int)S2);
        transpose_cl_kernel<<<(int)(S3 / 64), 256, 0, stream>>>(f3, ws + off3, (int)S3);
        dim3 grid(N, NCHUNK);
        roi_align_cl_kernel<<<grid, 256, 0, stream>>>(ws, boxes, out, N, C,
                                                      d0, d1, d2, d3,
                                                      off0, off1, off2, off3);
    } else {
        dim3 grid(C, N);
        roi_align_fallback_kernel<<<grid, FBLK, 0, stream>>>(f0, f1, f2, f3, boxes, out,
                                                             N, C, d0, d1, d2, d3);
    }
}

// Round 8
// 158.431 us; speedup vs baseline: 2.0404x; 1.1910x over previous
//
#include <hip/hip_runtime.h>
#include <math.h>

#define OUT 7
#define NVOX 343          // 7*7*7
#define NCHUNK 22         // ceil(343/16) voxel chunks per box

typedef unsigned short u16;
typedef unsigned int u32;

__device__ __forceinline__ u16 f32_to_bf16(float f) {
    u32 u = __float_as_uint(f);
    u32 r = (u + 0x7fffu + ((u >> 16) & 1u)) >> 16;   // RNE
    return (u16)r;
}
__device__ __forceinline__ float bf16_to_f32(u16 h) {
    return __uint_as_float(((u32)h) << 16);
}

__device__ __forceinline__ void axis_samp(float c, float fdim, int dim,
                                          int& lo, float& w0, float& w1) {
    float valid = (c > -1.0f && c < fdim) ? 1.0f : 0.0f;
    float cc = fminf(fmaxf(c, 0.0f), fdim - 1.0f);
    lo = (int)floorf(cc);
    float fr = cc - (float)lo;
    w0 = (1.0f - fr) * valid;
    w1 = fr * valid;     // == 0 whenever hi would clamp
}

__device__ __forceinline__ void box_setup(const float* bp,
                                          int d0, int d1, int d2_, int d3,
                                          int& l, int& dim, float& fdim,
                                          float& st0, float& st1, float& st2,
                                          float& bs0, float& bs1, float& bs2) {
    float b0 = bp[0], b1 = bp[1], b2 = bp[2];
    float b3 = bp[3], b4 = bp[4], b5 = bp[5];
    float vol = (b3 - b0) * (b4 - b1) * (b5 - b2);
    float s = cbrtf(vol);
    float lvl = floorf(4.0f + log2f(s / 160.0f) + 1e-6f);
    lvl = fminf(fmaxf(lvl, 2.0f), 5.0f);
    l = (int)lvl - 2;
    float scale;
    if (l == 0)      { dim = d0;  scale = 0.25f;    }
    else if (l == 1) { dim = d1;  scale = 0.125f;   }
    else if (l == 2) { dim = d2_; scale = 0.0625f;  }
    else             { dim = d3;  scale = 0.03125f; }
    fdim = (float)dim;
    st0 = b0 * scale; st1 = b1 * scale; st2 = b2 * scale;
    float e0 = fmaxf(b3 * scale - st0, 1.0f);
    float e1 = fmaxf(b4 * scale - st1, 1.0f);
    float e2 = fmaxf(b5 * scale - st2, 1.0f);
    bs0 = e0 * (1.0f / OUT); bs1 = e1 * (1.0f / OUT); bs2 = e2 * (1.0f / OUT);
}

// ---------------- fallback (R4-proven) ----------------
#define LDSF 11776
#define FBLK 512

__global__ __launch_bounds__(FBLK) void roi_align_fallback_kernel(
    const float* __restrict__ f0, const float* __restrict__ f1,
    const float* __restrict__ f2, const float* __restrict__ f3,
    const float* __restrict__ boxes, float* __restrict__ out,
    int N, int C, int d0, int d1, int d2_, int d3)
{
    __shared__ float lds[LDSF];
    const int c   = blockIdx.x;
    const int n   = blockIdx.y;
    const int tid = threadIdx.x;

    int l, dim; float fdim, st0, st1, st2, bs0, bs1, bs2;
    box_setup(boxes + n * 6, d0, d1, d2_, d3,
              l, dim, fdim, st0, st1, st2, bs0, bs1, bs2);
    const float* f = (l == 0) ? f0 : (l == 1) ? f1 : (l == 2) ? f2 : f3;

    const int dsq = dim * dim;
    const size_t dcube = (size_t)dim * dsq;
    const float* fc = f + (size_t)c * dcube;

    int x0 = (int)floorf(fminf(fmaxf(st0 + 0.25f * bs0, 0.0f), fdim - 1.0f));
    int x1 = min((int)floorf(fminf(fmaxf(st0 + 6.75f * bs0, 0.0f), fdim - 1.0f)) + 1, dim - 1);
    int y0 = (int)floorf(fminf(fmaxf(st1 + 0.25f * bs1, 0.0f), fdim - 1.0f));
    int y1 = min((int)floorf(fminf(fmaxf(st1 + 6.75f * bs1, 0.0f), fdim - 1.0f)) + 1, dim - 1);
    int z0 = (int)floorf(fminf(fmaxf(st2 + 0.25f * bs2, 0.0f), fdim - 1.0f));
    int z1 = min((int)floorf(fminf(fmaxf(st2 + 6.75f * bs2, 0.0f), fdim - 1.0f)) + 1, dim - 1);

    int nx = x1 - x0 + 1, ny = y1 - y0 + 1, nz = z1 - z0 + 1;
    int nzp = nz + 1;
    int nynzp = ny * nzp;
    int nrows = nx * ny;
    int nregp = nrows * nzp;

    int xl[2], yl[2], zl[2];
    float xw0[2], xw1[2], yw0[2], yw1[2], zw0[2], zw1[2];
    if (tid < NVOX) {
        int oz = tid % OUT;
        int oy = (tid / OUT) % OUT;
        int ox = tid / (OUT * OUT);
        #pragma unroll
        for (int r = 0; r < 2; ++r) {
            float off = 0.25f + 0.5f * (float)r;
            axis_samp(st0 + ((float)ox + off) * bs0, fdim, dim, xl[r], xw0[r], xw1[r]);
            axis_samp(st1 + ((float)oy + off) * bs1, fdim, dim, yl[r], yw0[r], yw1[r]);
            axis_samp(st2 + ((float)oz + off) * bs2, fdim, dim, zl[r], zw0[r], zw1[r]);
        }
    }

    if (nregp <= LDSF) {
        float rnzp = 1.0f / (float)nzp;
        float rny  = 1.0f / (float)ny;
        for (int e = tid; e < nregp; e += FBLK) {
            int row = (int)((float)e * rnzp);
            int zz = e - row * nzp;
            if (zz < 0)        { row -= 1; zz += nzp; }
            else if (zz >= nzp){ row += 1; zz -= nzp; }
            int rx = (int)((float)row * rny);
            int ry = row - rx * ny;
            if (ry < 0)        { rx -= 1; ry += ny; }
            else if (ry >= ny) { rx += 1; ry -= ny; }
            int zsrc = min(zz, nz - 1);
            lds[e] = fc[((size_t)(x0 + rx) * dim + (y0 + ry)) * dim + (z0 + zsrc)];
        }
        __syncthreads();

        if (tid < NVOX) {
            int XL[2], XH[2], YL[2], YH[2], ZL[2];
            #pragma unroll
            for (int r = 0; r < 2; ++r) {
                XL[r] = (xl[r] - x0) * nynzp;
                XH[r] = (min(xl[r] + 1, dim - 1) - x0) * nynzp;
                YL[r] = (yl[r] - y0) * nzp;
                YH[r] = (min(yl[r] + 1, dim - 1) - y0) * nzp;
                ZL[r] = zl[r] - z0;
            }
            float acc = 0.0f;
            #pragma unroll
            for (int rx2 = 0; rx2 < 2; ++rx2) {
                #pragma unroll
                for (int ry2 = 0; ry2 < 2; ++ry2) {
                    #pragma unroll
                    for (int rz2 = 0; rz2 < 2; ++rz2) {
                        const float* pll = lds + (XL[rx2] + YL[ry2] + ZL[rz2]);
                        const float* plh = lds + (XL[rx2] + YH[ry2] + ZL[rz2]);
                        const float* phl = lds + (XH[rx2] + YL[ry2] + ZL[rz2]);
                        const float* phh = lds + (XH[rx2] + YH[ry2] + ZL[rz2]);
                        float wz0 = zw0[rz2], wz1 = zw1[rz2];
                        float vx0 = yw0[ry2] * (wz0 * pll[0] + wz1 * pll[1])
                                  + yw1[ry2] * (wz0 * plh[0] + wz1 * plh[1]);
                        float vx1 = yw0[ry2] * (wz0 * phl[0] + wz1 * phl[1])
                                  + yw1[ry2] * (wz0 * phh[0] + wz1 * phh[1]);
                        acc += xw0[rx2] * vx0 + xw1[rx2] * vx1;
                    }
                }
            }
            out[((size_t)n * C + c) * NVOX + tid] = acc * 0.125f;
        }
    } else {
        if (tid < NVOX) {
            float acc = 0.0f;
            #pragma unroll
            for (int rx2 = 0; rx2 < 2; ++rx2) {
                const float* pxl = fc + (size_t)xl[rx2] * dsq;
                const float* pxh = fc + (size_t)min(xl[rx2] + 1, dim - 1) * dsq;
                float wx0 = xw0[rx2], wx1 = xw1[rx2];
                #pragma unroll
                for (int ry2 = 0; ry2 < 2; ++ry2) {
                    int ryl = yl[ry2] * dim;
                    int ryh = min(yl[ry2] + 1, dim - 1) * dim;
                    float wy0 = yw0[ry2], wy1 = yw1[ry2];
                    #pragma unroll
                    for (int rz2 = 0; rz2 < 2; ++rz2) {
                        int bZL = zl[rz2], bZH = min(zl[rz2] + 1, dim - 1);
                        float wz0 = zw0[rz2], wz1 = zw1[rz2];
                        float vx0 = wy0 * (wz0 * pxl[ryl + bZL] + wz1 * pxl[ryl + bZH])
                                  + wy1 * (wz0 * pxl[ryh + bZL] + wz1 * pxl[ryh + bZH]);
                        float vx1 = wy0 * (wz0 * pxh[ryl + bZL] + wz1 * pxh[ryl + bZH])
                                  + wy1 * (wz0 * pxh[ryh + bZL] + wz1 * pxh[ryh + bZH]);
                        acc += wx0 * vx0 + wx1 * vx1;
                    }
                }
            }
            out[((size_t)n * C + c) * NVOX + tid] = acc * 0.125f;
        }
    }
}

// ---------------- fused transpose: f32 (C,S) -> bf16 (S,C), all levels ----------------
__global__ __launch_bounds__(256) void transpose_bf16_kernel(
    const float* __restrict__ f0, const float* __restrict__ f1,
    const float* __restrict__ f2, const float* __restrict__ f3,
    u16* __restrict__ ws,
    int t1, int t2, int t3,              // cumulative tile counts for levels 0..2
    long S0, long S1, long S2, long S3,
    long off0, long off1, long off2, long off3)
{
    __shared__ u16 tile[64 * 65];
    int b = blockIdx.x;
    const float* src; u16* dst; long S; int tloc;
    if (b < t1)      { src = f0; dst = ws + off0; S = S0; tloc = b; }
    else if (b < t2) { src = f1; dst = ws + off1; S = S1; tloc = b - t1; }
    else if (b < t3) { src = f2; dst = ws + off2; S = S2; tloc = b - t2; }
    else             { src = f3; dst = ws + off3; S = S3; tloc = b - t3; }

    long s0 = (long)tloc * 64;
    int lane  = threadIdx.x & 63;
    int chunk = threadIdx.x >> 6;    // 0..3
    #pragma unroll
    for (int k = 0; k < 16; ++k) {
        int ch = chunk * 16 + k;
        tile[lane * 65 + ch] = f32_to_bf16(src[(size_t)ch * S + s0 + lane]);
    }
    __syncthreads();
    #pragma unroll
    for (int k = 0; k < 16; ++k) {
        int s = chunk * 16 + k;
        dst[(s0 + s) * 64 + lane] = tile[s * 65 + lane];
    }
}

// ---------------- main gather: channel-last bf16 ----------------
// grid: (N boxes, NCHUNK). tid = slot*16 + quad; lanes 0-15 share a voxel.
__global__ __launch_bounds__(256, 4) void roi_align_cl_kernel(
    const u16* __restrict__ ws, const float* __restrict__ boxes,
    float* __restrict__ out, int N, int C,
    int d0, int d1, int d2_, int d3,
    long off0, long off1, long off2, long off3)
{
    __shared__ float4 axtab[16 * 6];   // slot*6 + axis*2 + r : {offLo, offHi, w0, w1}
    __shared__ float ldsout[64 * 17];  // [ch*17 + slot]

    const int n    = blockIdx.x;       // box
    const int cb   = blockIdx.y * 16;  // chunk base voxel
    const int tid  = threadIdx.x;
    const int quad = tid & 15;
    const int slot = tid >> 4;

    int l, dim; float fdim, st0, st1, st2, bs0, bs1, bs2;
    box_setup(boxes + n * 6, d0, d1, d2_, d3,
              l, dim, fdim, st0, st1, st2, bs0, bs1, bs2);
    const u16* ftl = ws + ((l == 0) ? off0 : (l == 1) ? off1 : (l == 2) ? off2 : off3)
                   + quad * 4;
    const int dsq = dim * dim;

    // ---- per-voxel axis tables (16 threads, one voxel each) ----
    if (quad == 0) {
        int v = min(cb + slot, NVOX - 1);
        int o2 = v % OUT;
        int t7 = v / OUT;
        int o1 = t7 % OUT;
        int o0 = t7 / OUT;
        const int stA[3] = { dsq * 64, dim * 64, 64 };
        const float oA[3] = { (float)o0, (float)o1, (float)o2 };
        const float sA[3] = { st0, st1, st2 };
        const float bA[3] = { bs0, bs1, bs2 };
        #pragma unroll
        for (int a = 0; a < 3; ++a) {
            #pragma unroll
            for (int r = 0; r < 2; ++r) {
                float cc = sA[a] + (oA[a] + (0.25f + 0.5f * (float)r)) * bA[a];
                int lo; float w0, w1;
                axis_samp(cc, fdim, dim, lo, w0, w1);
                float4 e;
                e.x = __int_as_float(lo * stA[a]);
                e.y = __int_as_float(min(lo + 1, dim - 1) * stA[a]);
                e.z = w0; e.w = w1;
                axtab[slot * 6 + a * 2 + r] = e;
            }
        }
    }
    __syncthreads();

    const bool active = (cb + slot) < NVOX;
    if (active) {
        const float4* tb = &axtab[slot * 6];
        float4 ex0 = tb[0], ex1 = tb[1], ey0 = tb[2], ey1 = tb[3], ez0 = tb[4], ez1 = tb[5];
        float xw[4] = { ex0.z, ex0.w, ex1.z, ex1.w };
        int   xo[4] = { __float_as_int(ex0.x), __float_as_int(ex0.y),
                        __float_as_int(ex1.x), __float_as_int(ex1.y) };
        float yw[4] = { ey0.z, ey0.w, ey1.z, ey1.w };
        int   yo[4] = { __float_as_int(ey0.x), __float_as_int(ey0.y),
                        __float_as_int(ey1.x), __float_as_int(ey1.y) };
        float zw[4] = { ez0.z, ez0.w, ez1.z, ez1.w };
        int   zq[4] = { __float_as_int(ez0.x), __float_as_int(ez0.y),
                        __float_as_int(ez1.x), __float_as_int(ez1.y) };

        float4 acc = { 0.f, 0.f, 0.f, 0.f };
        #pragma unroll
        for (int i2 = 0; i2 < 4; ++i2) {
            float wxv = xw[i2];
            int a1 = xo[i2];
            #pragma unroll
            for (int j2 = 0; j2 < 4; ++j2) {
                float wxy = wxv * yw[j2];
                int a2 = a1 + yo[j2];
                #pragma unroll
                for (int k2 = 0; k2 < 4; ++k2) {
                    float w = wxy * zw[k2];
                    const ushort4 v = *(const ushort4*)(ftl + a2 + zq[k2]);
                    acc.x += w * bf16_to_f32(v.x);
                    acc.y += w * bf16_to_f32(v.y);
                    acc.z += w * bf16_to_f32(v.z);
                    acc.w += w * bf16_to_f32(v.w);
                }
            }
        }
        int chb = quad * 4;
        ldsout[(chb + 0) * 17 + slot] = acc.x * 0.125f;
        ldsout[(chb + 1) * 17 + slot] = acc.y * 0.125f;
        ldsout[(chb + 2) * 17 + slot] = acc.z * 0.125f;
        ldsout[(chb + 3) * 17 + slot] = acc.w * 0.125f;
    }
    __syncthreads();

    int nv = min(16, NVOX - cb);
    #pragma unroll
    for (int k = 0; k < 4; ++k) {
        int flat = k * 256 + tid;
        int ch = flat >> 4, vs = flat & 15;
        if (vs < nv)
            out[((size_t)n * C + ch) * NVOX + cb + vs] = ldsout[ch * 17 + vs];
    }
}

extern "C" void kernel_launch(void* const* d_in, const int* in_sizes, int n_in,
                              void* d_out, int out_size, void* d_ws, size_t ws_size,
                              hipStream_t stream) {
    const float* f0 = (const float*)d_in[0];
    const float* f1 = (const float*)d_in[1];
    const float* f2 = (const float*)d_in[2];
    const float* f3 = (const float*)d_in[3];
    const float* boxes = (const float*)d_in[4];
    float* out = (float*)d_out;

    int N = in_sizes[4] / 6;
    int C = out_size / (N * NVOX);

    auto cdim = [&](int sz) {
        int per_c = sz / C;
        return (int)(cbrtf((float)per_c) + 0.5f);
    };
    int d0 = cdim(in_sizes[0]);
    int d1 = cdim(in_sizes[1]);
    int d2 = cdim(in_sizes[2]);
    int d3 = cdim(in_sizes[3]);

    long S0 = (long)d0 * d0 * d0, S1 = (long)d1 * d1 * d1;
    long S2 = (long)d2 * d2 * d2, S3 = (long)d3 * d3 * d3;
    long off0 = 0, off1 = S0 * C, off2 = off1 + S1 * C, off3 = off2 + S2 * C;
    size_t need = (size_t)(off3 + S3 * C) * sizeof(u16);

    bool fast = (C == 64) && (ws_size >= need) &&
                (S0 % 64 == 0) && (S1 % 64 == 0) && (S2 % 64 == 0) && (S3 % 64 == 0);

    if (fast) {
        u16* ws = (u16*)d_ws;
        int t1 = (int)(S0 / 64);
        int t2 = t1 + (int)(S1 / 64);
        int t3 = t2 + (int)(S2 / 64);
        int tt = t3 + (int)(S3 / 64);
        transpose_bf16_kernel<<<tt, 256, 0, stream>>>(f0, f1, f2, f3, ws,
                                                      t1, t2, t3,
                                                      S0, S1, S2, S3,
                                                      off0, off1, off2, off3);
        dim3 grid(N, NCHUNK);
        roi_align_cl_kernel<<<grid, 256, 0, stream>>>(ws, boxes, out, N, C,
                                                      d0, d1, d2, d3,
                                                      off0, off1, off2, off3);
    } else {
        dim3 grid(C, N);
        roi_align_fallback_kernel<<<grid, FBLK, 0, stream>>>(f0, f1, f2, f3, boxes, out,
                                                             N, C, d0, d1, d2, d3);
    }
}